// Round 1
// baseline (29.035 us; speedup 1.0000x reference)
//
#include <hip/hip_runtime.h>

#define NUM_CAMS 6
#define C_FEAT   64
#define HF       16
#define WF       44
#define NPTS     (128*128*8)   // 131072
#define FEAT_ELEMS (NUM_CAMS*C_FEAT*HF*WF)  // 270336

// ---------------- kernel 1: proj = cam2img @ ego2cam (6 x 4x4) ----------------
__global__ void uvt_compute_proj(const float* __restrict__ ego2cam,
                                 const float* __restrict__ cam2img,
                                 float* __restrict__ proj) {
    int t = threadIdx.x;
    if (t < 96) {
        int n  = t >> 4;
        int ij = t & 15;
        int i = ij >> 2, j = ij & 3;
        const float* A = cam2img + n * 16;
        const float* B = ego2cam + n * 16;
        float s = 0.f;
        #pragma unroll
        for (int k = 0; k < 4; ++k) s += A[i*4 + k] * B[k*4 + j];
        proj[t] = s;
    }
}

// ---------------- kernel 2: transpose feats (N,C,H,W) -> (N,H,W,C) ------------
__global__ void uvt_transpose_feats(const float* __restrict__ in,
                                    float* __restrict__ out) {
    int idx = blockIdx.x * blockDim.x + threadIdx.x;
    if (idx >= FEAT_ELEMS) return;
    int c     = idx & 63;
    int rest  = idx >> 6;          // n*HF*WF + y*WF + x
    int x     = rest % WF;
    int rest2 = rest / WF;
    int y     = rest2 % HF;
    int n     = rest2 / HF;
    out[idx] = in[((n * C_FEAT + c) * HF + y) * WF + x];
}

// ---------------- kernel 3: project + bilinear sample + fuse ------------------
// block = 256 threads = 16 points x 16 channel-quads
__global__ __launch_bounds__(256) void uvt_fuse(
    const float* __restrict__ featsT,  // (6,16,44,64)
    const float* __restrict__ proj,    // (6,4,4)
    const float* __restrict__ vox,     // (3, NPTS)
    float* __restrict__ out)           // (64, NPTS)
{
    __shared__ float s_uf[NUM_CAMS][16];
    __shared__ float s_vf[NUM_CAMS][16];
    __shared__ int   s_val[NUM_CAMS][16];
    __shared__ float s_inv[16];

    const int tid  = threadIdx.x;
    const int pl   = tid & 15;     // local point
    const int quad = tid >> 4;     // channel quad 0..15
    const int p    = blockIdx.x * 16 + pl;

    // ---- phase 1: per (point, cam) projection params into LDS ----
    if (tid < 96) {
        const int cam = tid >> 4;  // 0..5, pl = tid & 15
        const float px = vox[p];
        const float py = vox[NPTS + p];
        const float pz = vox[2 * NPTS + p];
        const float* M = proj + cam * 16;
        const float ud = M[0]*px + M[1]*py + M[2]*pz  + M[3];
        const float vd = M[4]*px + M[5]*py + M[6]*pz  + M[7];
        const float d  = M[8]*px + M[9]*py + M[10]*pz + M[11];
        const float inv = 1.0f / (d + 1e-6f);
        const float u = ud * inv;
        const float v = vd * inv;
        const bool valid = (d > 0.1f) && (u >= 0.f) && (u <= 703.f)
                                      && (v >= 0.f) && (v <= 255.f);
        s_uf[cam][pl]  = u * (1.0f / 16.0f);
        s_vf[cam][pl]  = v * (1.0f / 16.0f);
        s_val[cam][pl] = valid ? 1 : 0;
    }
    __syncthreads();
    if (tid < 16) {
        int cnt = 0;
        #pragma unroll
        for (int c = 0; c < NUM_CAMS; ++c) cnt += s_val[c][tid];
        s_inv[tid] = 1.0f / (float)(cnt > 0 ? cnt : 1);
    }
    __syncthreads();

    // ---- phase 2: gather + weighted accumulate ----
    float4 acc = make_float4(0.f, 0.f, 0.f, 0.f);
    #pragma unroll
    for (int cam = 0; cam < NUM_CAMS; ++cam) {
        if (!s_val[cam][pl]) continue;
        const float uf = s_uf[cam][pl];
        const float vf = s_vf[cam][pl];
        const float xf = floorf(uf), yf = floorf(vf);
        const int   x0 = (int)xf,   y0 = (int)yf;
        const float wx1 = uf - xf,  wy1 = vf - yf;
        const float wx0 = 1.f - wx1, wy0 = 1.f - wy1;
        const float* base = featsT + (((cam * HF + y0) * WF + x0) << 6) + (quad << 2);

        {   // corner (x0, y0): always in-bounds when valid
            const float w = wx0 * wy0;
            const float4 f = *(const float4*)(base);
            acc.x += w * f.x; acc.y += w * f.y; acc.z += w * f.z; acc.w += w * f.w;
        }
        if (x0 + 1 < WF) {
            const float w = wx1 * wy0;
            const float4 f = *(const float4*)(base + 64);
            acc.x += w * f.x; acc.y += w * f.y; acc.z += w * f.z; acc.w += w * f.w;
        }
        if (y0 + 1 < HF) {
            {
                const float w = wx0 * wy1;
                const float4 f = *(const float4*)(base + WF * 64);
                acc.x += w * f.x; acc.y += w * f.y; acc.z += w * f.z; acc.w += w * f.w;
            }
            if (x0 + 1 < WF) {
                const float w = wx1 * wy1;
                const float4 f = *(const float4*)(base + WF * 64 + 64);
                acc.x += w * f.x; acc.y += w * f.y; acc.z += w * f.z; acc.w += w * f.w;
            }
        }
    }

    const float inv = s_inv[pl];
    const int cbase = quad << 2;
    out[(cbase + 0) * NPTS + p] = acc.x * inv;
    out[(cbase + 1) * NPTS + p] = acc.y * inv;
    out[(cbase + 2) * NPTS + p] = acc.z * inv;
    out[(cbase + 3) * NPTS + p] = acc.w * inv;
}

// ---------------------------------------------------------------------------
extern "C" void kernel_launch(void* const* d_in, const int* in_sizes, int n_in,
                              void* d_out, int out_size, void* d_ws, size_t ws_size,
                              hipStream_t stream) {
    const float* img_feats = (const float*)d_in[0];  // (6,64,16,44)
    const float* ego2cam   = (const float*)d_in[1];  // (6,4,4)
    const float* cam2img   = (const float*)d_in[2];  // (6,4,4)
    const float* vox       = (const float*)d_in[3];  // (3,8,128,128)
    float* out = (float*)d_out;                      // (1,64,8,128,128)

    float* featsT = (float*)d_ws;                    // 270336 floats
    float* proj   = featsT + FEAT_ELEMS;             // 96 floats

    uvt_compute_proj<<<1, 128, 0, stream>>>(ego2cam, cam2img, proj);
    uvt_transpose_feats<<<(FEAT_ELEMS + 255) / 256, 256, 0, stream>>>(img_feats, featsT);
    uvt_fuse<<<NPTS / 16, 256, 0, stream>>>(featsT, proj, vox, out);
}

// Round 2
// 26.545 us; speedup vs baseline: 1.0938x; 1.0938x over previous
//
#include <hip/hip_runtime.h>

#define NUM_CAMS 6
#define C_FEAT   64
#define HF       16
#define WF       44
#define NPTS     (128*128*8)   // 131072
#define FEAT_ELEMS (NUM_CAMS*C_FEAT*HF*WF)  // 270336

// ---------------- kernel 1: transpose feats (N,C,H,W) -> (N,H,W,C) ------------
__global__ void uvt_transpose_feats(const float* __restrict__ in,
                                    float* __restrict__ out) {
    int idx = blockIdx.x * blockDim.x + threadIdx.x;
    if (idx >= FEAT_ELEMS) return;
    int c     = idx & 63;
    int rest  = idx >> 6;          // n*HF*WF + y*WF + x
    int x     = rest % WF;
    int rest2 = rest / WF;
    int y     = rest2 % HF;
    int n     = rest2 / HF;
    out[idx] = in[((n * C_FEAT + c) * HF + y) * WF + x];
}

// ---------------- kernel 2: project + bilinear sample + fuse ------------------
// block = 256 threads; lanes: quad = tid&15 (channel quad), pl = tid>>4 (point)
// => per wave: 16 quads x 4 points -> gathers are 4 x 256B contiguous segments
__global__ __launch_bounds__(256) void uvt_fuse(
    const float* __restrict__ featsT,   // (6,16,44,64)
    const float* __restrict__ ego2cam,  // (6,4,4)
    const float* __restrict__ cam2img,  // (6,4,4)
    const float* __restrict__ vox,      // (3, NPTS)
    float* __restrict__ out)            // (64, NPTS)
{
    __shared__ float s_proj[NUM_CAMS][12];
    __shared__ float s_uf[NUM_CAMS][16];
    __shared__ float s_vf[NUM_CAMS][16];
    __shared__ int   s_val[NUM_CAMS][16];
    __shared__ float s_inv[16];
    __shared__ float s_out[16][65];     // +1 pad: conflict-free transpose

    const int tid = threadIdx.x;
    const int p0  = blockIdx.x * 16;

    // ---- phase 0: proj = cam2img @ ego2cam (rows 0..2 used) ----
    if (tid < 72) {
        const int cam = tid / 12;
        const int e   = tid - cam * 12;
        const int i = e >> 2, j = e & 3;
        const float* A = cam2img + cam * 16;
        const float* B = ego2cam + cam * 16;
        float s = 0.f;
        #pragma unroll
        for (int k = 0; k < 4; ++k) s += A[i*4 + k] * B[k*4 + j];
        s_proj[cam][e] = s;
    }
    __syncthreads();

    // ---- phase 1: per (point, cam) projection params ----
    if (tid < 96) {
        const int cam = tid >> 4;
        const int lp  = tid & 15;
        const int p   = p0 + lp;
        const float px = vox[p];
        const float py = vox[NPTS + p];
        const float pz = vox[2 * NPTS + p];
        const float* M = s_proj[cam];
        const float ud = M[0]*px + M[1]*py + M[2]*pz  + M[3];
        const float vd = M[4]*px + M[5]*py + M[6]*pz  + M[7];
        const float d  = M[8]*px + M[9]*py + M[10]*pz + M[11];
        const float inv = 1.0f / (d + 1e-6f);
        const float u = ud * inv;
        const float v = vd * inv;
        const bool valid = (d > 0.1f) && (u >= 0.f) && (u <= 703.f)
                                      && (v >= 0.f) && (v <= 255.f);
        s_uf[cam][lp]  = u * (1.0f / 16.0f);
        s_vf[cam][lp]  = v * (1.0f / 16.0f);
        s_val[cam][lp] = valid ? 1 : 0;
    }
    __syncthreads();
    if (tid < 16) {
        int cnt = 0;
        #pragma unroll
        for (int c = 0; c < NUM_CAMS; ++c) cnt += s_val[c][tid];
        s_inv[tid] = 1.0f / (float)(cnt > 0 ? cnt : 1);
    }
    __syncthreads();

    // ---- phase 2: gather + weighted accumulate ----
    const int quad = tid & 15;   // channel quad (contiguous across 16 lanes)
    const int pl   = tid >> 4;   // local point (4 per wave)
    float4 acc = make_float4(0.f, 0.f, 0.f, 0.f);
    #pragma unroll
    for (int cam = 0; cam < NUM_CAMS; ++cam) {
        if (!s_val[cam][pl]) continue;   // whole-wave skip when 4 pts invalid
        const float uf = s_uf[cam][pl];
        const float vf = s_vf[cam][pl];
        const float xf = floorf(uf), yf = floorf(vf);
        const int   x0 = (int)xf,   y0 = (int)yf;
        const float wx1 = uf - xf,  wy1 = vf - yf;
        const float wx0 = 1.f - wx1, wy0 = 1.f - wy1;
        const float* base = featsT + (((cam * HF + y0) * WF + x0) << 6) + (quad << 2);

        {   // (x0,y0) always in-bounds when valid
            const float w = wx0 * wy0;
            const float4 f = *(const float4*)(base);
            acc.x += w * f.x; acc.y += w * f.y; acc.z += w * f.z; acc.w += w * f.w;
        }
        if (x0 + 1 < WF) {
            const float w = wx1 * wy0;
            const float4 f = *(const float4*)(base + 64);
            acc.x += w * f.x; acc.y += w * f.y; acc.z += w * f.z; acc.w += w * f.w;
        }
        if (y0 + 1 < HF) {
            {
                const float w = wx0 * wy1;
                const float4 f = *(const float4*)(base + WF * 64);
                acc.x += w * f.x; acc.y += w * f.y; acc.z += w * f.z; acc.w += w * f.w;
            }
            if (x0 + 1 < WF) {
                const float w = wx1 * wy1;
                const float4 f = *(const float4*)(base + WF * 64 + 64);
                acc.x += w * f.x; acc.y += w * f.y; acc.z += w * f.z; acc.w += w * f.w;
            }
        }
    }

    // ---- phase 3: transpose through LDS, coalesced store ----
    const float inv = s_inv[pl];
    s_out[pl][quad * 4 + 0] = acc.x * inv;
    s_out[pl][quad * 4 + 1] = acc.y * inv;
    s_out[pl][quad * 4 + 2] = acc.z * inv;
    s_out[pl][quad * 4 + 3] = acc.w * inv;
    __syncthreads();

    #pragma unroll
    for (int i = 0; i < 4; ++i) {
        const int idx = tid + 256 * i;       // 0..1023
        const int c   = idx >> 4;            // channel
        const int lp  = idx & 15;            // point
        out[c * NPTS + p0 + lp] = s_out[lp][c];
    }
}

// ---------------------------------------------------------------------------
extern "C" void kernel_launch(void* const* d_in, const int* in_sizes, int n_in,
                              void* d_out, int out_size, void* d_ws, size_t ws_size,
                              hipStream_t stream) {
    const float* img_feats = (const float*)d_in[0];  // (6,64,16,44)
    const float* ego2cam   = (const float*)d_in[1];  // (6,4,4)
    const float* cam2img   = (const float*)d_in[2];  // (6,4,4)
    const float* vox       = (const float*)d_in[3];  // (3,8,128,128)
    float* out = (float*)d_out;                      // (1,64,8,128,128)

    float* featsT = (float*)d_ws;                    // 270336 floats

    uvt_transpose_feats<<<(FEAT_ELEMS + 255) / 256, 256, 0, stream>>>(img_feats, featsT);
    uvt_fuse<<<NPTS / 16, 256, 0, stream>>>(featsT, ego2cam, cam2img, vox, out);
}

// Round 3
// 22.998 us; speedup vs baseline: 1.2625x; 1.1542x over previous
//
#include <hip/hip_runtime.h>

#define NUM_CAMS 6
#define C_FEAT   64
#define HF       16
#define WF       44
#define NPTS     (128*128*8)   // 131072
#define FEAT_ELEMS (NUM_CAMS*C_FEAT*HF*WF)  // 270336
#define PPB      32            // points per block
#define NTHREADS 512

// ---------------- kernel 1: transpose feats (N,C,H,W) -> (N,H,W,C) ------------
__global__ void uvt_transpose_feats(const float* __restrict__ in,
                                    float* __restrict__ out) {
    int idx = blockIdx.x * blockDim.x + threadIdx.x;
    if (idx >= FEAT_ELEMS) return;
    int c     = idx & 63;
    int rest  = idx >> 6;          // n*HF*WF + y*WF + x
    int x     = rest % WF;
    int rest2 = rest / WF;
    int y     = rest2 % HF;
    int n     = rest2 / HF;
    out[idx] = in[((n * C_FEAT + c) * HF + y) * WF + x];
}

// per (point,cam) precomputed sampling params: 4 weights + base/step offsets
struct alignas(32) PC {
    float4 w;   // w00, w10, w01, w11 (zeroed for OOB corners / invalid point)
    int4   o;   // off (element base), dx (0|64), dy (0|WF*64), valid (0|1)
};

// ---------------- kernel 2: project + bilinear sample + fuse ------------------
// 512 threads = 32 points x 16 channel-quads; quad = tid&15, pl = tid>>4
// wave: 16 quads x 4 points -> gathers are 4 x 256B contiguous segments
__global__ __launch_bounds__(NTHREADS) void uvt_fuse(
    const float* __restrict__ featsT,   // (6,16,44,64)
    const float* __restrict__ ego2cam,  // (6,4,4)
    const float* __restrict__ cam2img,  // (6,4,4)
    const float* __restrict__ vox,      // (3, NPTS)
    float* __restrict__ out)            // (64, NPTS)
{
    __shared__ PC    s_pc[NUM_CAMS][PPB];
    __shared__ float s_out[PPB][65];    // stride 65: 2-way max on touched ops

    const int tid = threadIdx.x;
    const int p0  = blockIdx.x * PPB;

    // ---- phase 1: per (point,cam) projection + sampling params ----
    if (tid < NUM_CAMS * PPB) {         // 192 threads
        const int cam = tid >> 5;       // 0..5
        const int lp  = tid & 31;
        const int p   = p0 + lp;

        // proj = cam2img[cam] @ ego2cam[cam], rows 0..2 (redundant per lane; tiny)
        const float* A = cam2img + cam * 16;
        const float* B = ego2cam + cam * 16;
        float M[12];
        #pragma unroll
        for (int i = 0; i < 3; ++i)
            #pragma unroll
            for (int j = 0; j < 4; ++j) {
                float s = 0.f;
                #pragma unroll
                for (int k = 0; k < 4; ++k) s += A[i*4 + k] * B[k*4 + j];
                M[i*4 + j] = s;
            }

        const float px = vox[p];
        const float py = vox[NPTS + p];
        const float pz = vox[2 * NPTS + p];
        const float ud = M[0]*px + M[1]*py + M[2]*pz  + M[3];
        const float vd = M[4]*px + M[5]*py + M[6]*pz  + M[7];
        const float d  = M[8]*px + M[9]*py + M[10]*pz + M[11];
        const float id = 1.0f / (d + 1e-6f);
        const float u  = ud * id;
        const float v  = vd * id;
        const bool valid = (d > 0.1f) && (u >= 0.f) && (u <= 703.f)
                                      && (v >= 0.f) && (v <= 255.f);
        PC pc;
        if (valid) {
            const float x  = u * 0.0625f;       // featmap coords (= grid_sample x)
            const float y  = v * 0.0625f;
            const float xf = floorf(x), yf = floorf(y);
            const int   x0 = (int)xf,   y0 = (int)yf;   // x0 in [0,43], y0 in [0,15]
            const float wx1 = x - xf,  wy1 = y - yf;
            const float wx0 = 1.f - wx1, wy0 = 1.f - wy1;
            const bool bx = (x0 < WF - 1);      // x0+1 in bounds
            const bool by = (y0 < HF - 1);      // y0+1 in bounds
            pc.w = make_float4(wx0 * wy0,
                               bx ? wx1 * wy0 : 0.f,
                               by ? wx0 * wy1 : 0.f,
                               (bx && by) ? wx1 * wy1 : 0.f);
            pc.o = make_int4(((cam * HF + y0) * WF + x0) << 6,
                             bx ? C_FEAT : 0,
                             by ? WF * C_FEAT : 0,
                             1);
        } else {
            pc.w = make_float4(0.f, 0.f, 0.f, 0.f);
            pc.o = make_int4(0, 0, 0, 0);
        }
        s_pc[cam][lp] = pc;
    }
    __syncthreads();

    // ---- phase 2: branchless gather + weighted accumulate ----
    const int quad = tid & 15;
    const int pl   = tid >> 4;
    float  cnt = 0.f;
    float4 acc = make_float4(0.f, 0.f, 0.f, 0.f);
    #pragma unroll
    for (int cam = 0; cam < NUM_CAMS; ++cam) {
        const float4 w = s_pc[cam][pl].w;
        const int4   o = s_pc[cam][pl].o;
        cnt += (float)o.w;
        if (o.w) {   // exec-mask predication; no inner branches
            const float* b = featsT + o.x + (quad << 2);
            const float4 f00 = *(const float4*)(b);
            const float4 f10 = *(const float4*)(b + o.y);
            const float4 f01 = *(const float4*)(b + o.z);
            const float4 f11 = *(const float4*)(b + o.y + o.z);
            acc.x = fmaf(w.x, f00.x, fmaf(w.y, f10.x, fmaf(w.z, f01.x, fmaf(w.w, f11.x, acc.x))));
            acc.y = fmaf(w.x, f00.y, fmaf(w.y, f10.y, fmaf(w.z, f01.y, fmaf(w.w, f11.y, acc.y))));
            acc.z = fmaf(w.x, f00.z, fmaf(w.y, f10.z, fmaf(w.z, f01.z, fmaf(w.w, f11.z, acc.z))));
            acc.w = fmaf(w.x, f00.w, fmaf(w.y, f10.w, fmaf(w.z, f01.w, fmaf(w.w, f11.w, acc.w))));
        }
    }

    const float inv = 1.0f / fmaxf(cnt, 1.0f);
    s_out[pl][quad * 4 + 0] = acc.x * inv;
    s_out[pl][quad * 4 + 1] = acc.y * inv;
    s_out[pl][quad * 4 + 2] = acc.z * inv;
    s_out[pl][quad * 4 + 3] = acc.w * inv;
    __syncthreads();

    // ---- phase 3: coalesced store (128B segments) ----
    #pragma unroll
    for (int i = 0; i < 4; ++i) {
        const int idx = tid + NTHREADS * i;   // 0..2047
        const int c   = idx >> 5;             // channel
        const int lp  = idx & 31;             // point
        out[c * NPTS + p0 + lp] = s_out[lp][c];
    }
}

// ---------------------------------------------------------------------------
extern "C" void kernel_launch(void* const* d_in, const int* in_sizes, int n_in,
                              void* d_out, int out_size, void* d_ws, size_t ws_size,
                              hipStream_t stream) {
    const float* img_feats = (const float*)d_in[0];  // (6,64,16,44)
    const float* ego2cam   = (const float*)d_in[1];  // (6,4,4)
    const float* cam2img   = (const float*)d_in[2];  // (6,4,4)
    const float* vox       = (const float*)d_in[3];  // (3,8,128,128)
    float* out = (float*)d_out;                      // (1,64,8,128,128)

    float* featsT = (float*)d_ws;                    // 270336 floats

    uvt_transpose_feats<<<(FEAT_ELEMS + 255) / 256, 256, 0, stream>>>(img_feats, featsT);
    uvt_fuse<<<NPTS / PPB, NTHREADS, 0, stream>>>(featsT, ego2cam, cam2img, vox, out);
}

// Round 4
// 22.460 us; speedup vs baseline: 1.2928x; 1.0240x over previous
//
#include <hip/hip_runtime.h>
#include <hip/hip_fp16.h>

#define NUM_CAMS 6
#define C_FEAT   64
#define HF       16
#define WF       44
#define NPTS     (128*128*8)   // 131072
#define FEAT_ELEMS (NUM_CAMS*C_FEAT*HF*WF)  // 270336
#define PPB      32            // points per block
#define NTHREADS 512

// -------- kernel 1: transpose + fp16 convert (N,C,H,W) -> (N,H,W,C) half ----
__global__ void uvt_transpose_feats_h(const float* __restrict__ in,
                                      __half* __restrict__ out) {
    int idx = blockIdx.x * blockDim.x + threadIdx.x;
    if (idx >= FEAT_ELEMS) return;
    int c     = idx & 63;
    int rest  = idx >> 6;          // n*HF*WF + y*WF + x
    int x     = rest % WF;
    int rest2 = rest / WF;
    int y     = rest2 % HF;
    int n     = rest2 / HF;
    out[idx] = __float2half(in[((n * C_FEAT + c) * HF + y) * WF + x]);
}

// per (point,cam) sampling params: duplicated half2 weights + offsets
struct alignas(32) PC {
    __half2 w00, w10, w01, w11;   // each = {w,w}; zeroed for OOB corner/invalid
    int base, dx, dy, valid;      // element offsets (halves); dx=0|64, dy=0|WF*64
};

// -------- kernel 2: project + packed-half bilinear sample + fuse ------------
// 512 threads = 32 points x 16 channel-quads; quad = tid&15, pl = tid>>4
__global__ __launch_bounds__(NTHREADS) void uvt_fuse(
    const __half* __restrict__ featsT,  // (6,16,44,64) fp16
    const float* __restrict__ ego2cam,  // (6,4,4)
    const float* __restrict__ cam2img,  // (6,4,4)
    const float* __restrict__ vox,      // (3, NPTS)
    float* __restrict__ out)            // (64, NPTS)
{
    __shared__ PC    s_pc[NUM_CAMS][PPB];
    __shared__ int   s_vmask[PPB];
    __shared__ float s_inv[PPB];
    __shared__ float s_out[PPB][65];

    const int tid = threadIdx.x;
    const int p0  = blockIdx.x * PPB;

    // ---- phase 1: per (point,cam) projection + sampling params ----
    if (tid < NUM_CAMS * PPB) {         // 192 threads
        const int cam = tid >> 5;       // 0..5
        const int lp  = tid & 31;
        const int p   = p0 + lp;

        const float* A = cam2img + cam * 16;
        const float* B = ego2cam + cam * 16;
        float M[12];
        #pragma unroll
        for (int i = 0; i < 3; ++i)
            #pragma unroll
            for (int j = 0; j < 4; ++j) {
                float s = 0.f;
                #pragma unroll
                for (int k = 0; k < 4; ++k) s += A[i*4 + k] * B[k*4 + j];
                M[i*4 + j] = s;
            }

        const float px = vox[p];
        const float py = vox[NPTS + p];
        const float pz = vox[2 * NPTS + p];
        const float ud = M[0]*px + M[1]*py + M[2]*pz  + M[3];
        const float vd = M[4]*px + M[5]*py + M[6]*pz  + M[7];
        const float d  = M[8]*px + M[9]*py + M[10]*pz + M[11];
        const float id = 1.0f / (d + 1e-6f);
        const float u  = ud * id;
        const float v  = vd * id;
        const bool valid = (d > 0.1f) && (u >= 0.f) && (u <= 703.f)
                                      && (v >= 0.f) && (v <= 255.f);
        PC pc;
        if (valid) {
            const float x  = u * 0.0625f;
            const float y  = v * 0.0625f;
            const float xf = floorf(x), yf = floorf(y);
            const int   x0 = (int)xf,   y0 = (int)yf;   // x0 in [0,43], y0 in [0,15]
            const float wx1 = x - xf,  wy1 = y - yf;
            const float wx0 = 1.f - wx1, wy0 = 1.f - wy1;
            const bool bx = (x0 < WF - 1);
            const bool by = (y0 < HF - 1);
            pc.w00 = __float2half2_rn(wx0 * wy0);
            pc.w10 = __float2half2_rn(bx ? wx1 * wy0 : 0.f);
            pc.w01 = __float2half2_rn(by ? wx0 * wy1 : 0.f);
            pc.w11 = __float2half2_rn((bx && by) ? wx1 * wy1 : 0.f);
            pc.base = ((cam * HF + y0) * WF + x0) << 6;
            pc.dx   = bx ? C_FEAT : 0;
            pc.dy   = by ? WF * C_FEAT : 0;
            pc.valid = 1;
        } else {
            pc.w00 = pc.w10 = pc.w01 = pc.w11 = __float2half2_rn(0.f);
            pc.base = pc.dx = pc.dy = 0;
            pc.valid = 0;
        }
        s_pc[cam][lp] = pc;
    }
    __syncthreads();

    if (tid < PPB) {
        int m = 0, c = 0;
        #pragma unroll
        for (int cam = 0; cam < NUM_CAMS; ++cam) {
            const int v = s_pc[cam][tid].valid;
            m |= v << cam;
            c += v;
        }
        s_vmask[tid] = m;
        s_inv[tid]   = 1.0f / (float)(c > 0 ? c : 1);
    }
    __syncthreads();

    // ---- phase 2: validity-gated packed-half gather + accumulate ----
    const int quad = tid & 15;
    const int pl   = tid >> 4;
    const int vm   = s_vmask[pl];
    float4 acc = make_float4(0.f, 0.f, 0.f, 0.f);
    #pragma unroll
    for (int cam = 0; cam < NUM_CAMS; ++cam) {
        if ((vm >> cam) & 1) {    // exec-masked: no LDS/TA traffic when invalid
            const PC pc = s_pc[cam][pl];
            const __half* b = featsT + pc.base + (quad << 2);
            const uint2 r00 = *(const uint2*)(b);
            const uint2 r10 = *(const uint2*)(b + pc.dx);
            const uint2 r01 = *(const uint2*)(b + pc.dy);
            const uint2 r11 = *(const uint2*)(b + pc.dx + pc.dy);

            __half2 s0 = __hmul2(pc.w00, __builtin_bit_cast(__half2, r00.x));
            s0 = __hfma2(pc.w10, __builtin_bit_cast(__half2, r10.x), s0);
            s0 = __hfma2(pc.w01, __builtin_bit_cast(__half2, r01.x), s0);
            s0 = __hfma2(pc.w11, __builtin_bit_cast(__half2, r11.x), s0);
            __half2 s1 = __hmul2(pc.w00, __builtin_bit_cast(__half2, r00.y));
            s1 = __hfma2(pc.w10, __builtin_bit_cast(__half2, r10.y), s1);
            s1 = __hfma2(pc.w01, __builtin_bit_cast(__half2, r01.y), s1);
            s1 = __hfma2(pc.w11, __builtin_bit_cast(__half2, r11.y), s1);

            const float2 f0 = __half22float2(s0);
            const float2 f1 = __half22float2(s1);
            acc.x += f0.x; acc.y += f0.y; acc.z += f1.x; acc.w += f1.y;
        }
    }

    const float inv = s_inv[pl];
    s_out[pl][quad * 4 + 0] = acc.x * inv;
    s_out[pl][quad * 4 + 1] = acc.y * inv;
    s_out[pl][quad * 4 + 2] = acc.z * inv;
    s_out[pl][quad * 4 + 3] = acc.w * inv;
    __syncthreads();

    // ---- phase 3: coalesced store (128B segments) ----
    #pragma unroll
    for (int i = 0; i < 4; ++i) {
        const int idx = tid + NTHREADS * i;   // 0..2047
        const int c   = idx >> 5;             // channel
        const int lp  = idx & 31;             // point
        out[c * NPTS + p0 + lp] = s_out[lp][c];
    }
}

// ---------------------------------------------------------------------------
extern "C" void kernel_launch(void* const* d_in, const int* in_sizes, int n_in,
                              void* d_out, int out_size, void* d_ws, size_t ws_size,
                              hipStream_t stream) {
    const float* img_feats = (const float*)d_in[0];  // (6,64,16,44)
    const float* ego2cam   = (const float*)d_in[1];  // (6,4,4)
    const float* cam2img   = (const float*)d_in[2];  // (6,4,4)
    const float* vox       = (const float*)d_in[3];  // (3,8,128,128)
    float* out = (float*)d_out;                      // (1,64,8,128,128)

    __half* featsT = (__half*)d_ws;                  // 270336 halves (~0.54 MB)

    uvt_transpose_feats_h<<<(FEAT_ELEMS + 255) / 256, 256, 0, stream>>>(img_feats, featsT);
    uvt_fuse<<<NPTS / PPB, NTHREADS, 0, stream>>>(featsT, ego2cam, cam2img, vox, out);
}